// Round 9
// baseline (286.806 us; speedup 1.0000x reference)
//
#include <hip/hip_runtime.h>
#include <math.h>

#define B_ 32
#define HW_ 4096
#define N_ 16
#define C_ 128
#define F_ 512
#define ITERS_ 3
#define EPS_LN 1e-5f
#define EPS_ATTN 1e-5f

typedef __attribute__((ext_vector_type(8))) short short8;
typedef __attribute__((ext_vector_type(4))) float f32x4;

static __device__ __forceinline__ unsigned short f2b(float f) {
    union { float f; unsigned u; } v; v.f = f;
    unsigned r = v.u + 0x7fffu + ((v.u >> 16) & 1u);
    return (unsigned short)(r >> 16);
}
static __device__ __forceinline__ float blo(unsigned u) {
    union { unsigned u; float f; } v; v.u = u << 16; return v.f;
}
static __device__ __forceinline__ float bhi(unsigned u) {
    union { unsigned u; float f; } v; v.u = u & 0xffff0000u; return v.f;
}
// async global->LDS, 16B per lane; LDS dest is wave-uniform base + lane*16
static __device__ __forceinline__ void gload_lds16(const void* g, void* l) {
    __builtin_amdgcn_global_load_lds(
        (const __attribute__((address_space(1))) unsigned int*)g,
        (__attribute__((address_space(3))) unsigned int*)l, 16, 0, 0);
}

// ---------------------------------------------------------------------------
// One-time prep (unchanged from r7).
// ---------------------------------------------------------------------------
__global__ __launch_bounds__(256) void k_prep(
    const float* __restrict__ Wk, const float* __restrict__ Wv,
    const float* __restrict__ wih, const float* __restrict__ whh,
    const float* __restrict__ w1, const float* __restrict__ w2,
    unsigned short* __restrict__ Wk_sw, unsigned short* __restrict__ Wv_sw,
    unsigned short* __restrict__ wihT, unsigned short* __restrict__ whhT,
    unsigned short* __restrict__ w1T, unsigned short* __restrict__ w2T,
    const float* __restrict__ query, const float* __restrict__ lnqg,
    const float* __restrict__ lnqb, const float* __restrict__ Wq,
    float* __restrict__ wqTf, unsigned short* __restrict__ qn_g)
{
    __shared__ __align__(16) float xq[16 * 128];
    int tid = threadIdx.x;
    int blk = blockIdx.x;
    if (blk < 32) {
        int t = blk * 256 + tid;           // float4-group id, 0..8191
        const float* src; unsigned short* dst; int off;
        if (t < 4096) { src = Wk; dst = Wk_sw; off = t; }
        else          { src = Wv; dst = Wv_sw; off = t - 4096; }
        float4 a = ((const float4*)src)[off];
        uint2 p;
        p.x = (unsigned)f2b(a.x) | ((unsigned)f2b(a.y) << 16);
        p.y = (unsigned)f2b(a.z) | ((unsigned)f2b(a.w) << 16);
        int r = off >> 5;                  // row 0..127
        int j = off & 31;                  // 4-short group within row
        int cg2 = j >> 1, half = j & 1;    // 8-short col-group + half
        int dsw = r * 128 + (((cg2 ^ (r & 7)) << 3)) + (half << 2);
        *(uint2*)(dst + dsw) = p;
        return;
    }
    if (blk < 256) {
        const float* src; unsigned short* dst; int o, g, id, Cin;
        if (blk < 80) {         // wih: R=384, Cin=128
            id = (blk - 32) * 256 + tid;
            g = id / 384; o = id - g * 384;
            src = wih; dst = wihT; Cin = 128;
        } else if (blk < 128) { // whh: R=384
            id = (blk - 80) * 256 + tid;
            g = id / 384; o = id - g * 384;
            src = whh; dst = whhT; Cin = 128;
        } else if (blk < 192) { // w1: R=512, Cin=128
            id = (blk - 128) * 256 + tid;
            g = id >> 9; o = id & 511;
            src = w1; dst = w1T; Cin = 128;
        } else {                // w2: R=128, Cin=512
            id = (blk - 192) * 256 + tid;
            g = id >> 7; o = id & 127;
            src = w2; dst = w2T; Cin = 512;
        }
        float4 a = *(const float4*)(src + o * Cin + g * 4);
        uint2 p;
        p.x = (unsigned)f2b(a.x) | ((unsigned)f2b(a.y) << 16);
        p.y = (unsigned)f2b(a.z) | ((unsigned)f2b(a.w) << 16);
        *(uint2*)(dst + id * 4) = p;
        return;
    }
    if (blk >= 288) {
        int t = (blk - 288) * 256 + tid;   // 0..4095
        int c = t & 127, g = t >> 7;       // g 0..31
        float4 a = *(const float4*)(Wq + c * 128 + g * 4);
        ((float4*)wqTf)[g * 128 + c] = a;
        return;
    }
    int b = blk - 256;
    int n = tid >> 4, part = tid & 15;
    int row = b * 16 + n;
    const float4* x4 = (const float4*)(query + row * 128 + part * 8);
    float4 x0 = x4[0], x1 = x4[1];
    float s = x0.x + x0.y + x0.z + x0.w + x1.x + x1.y + x1.z + x1.w;
    float ss = x0.x * x0.x + x0.y * x0.y + x0.z * x0.z + x0.w * x0.w +
               x1.x * x1.x + x1.y * x1.y + x1.z * x1.z + x1.w * x1.w;
    s += __shfl_xor(s, 1); s += __shfl_xor(s, 2); s += __shfl_xor(s, 4); s += __shfl_xor(s, 8);
    ss += __shfl_xor(ss, 1); ss += __shfl_xor(ss, 2); ss += __shfl_xor(ss, 4); ss += __shfl_xor(ss, 8);
    float mean = s * (1.f / 128.f);
    float var = ss * (1.f / 128.f) - mean * mean;
    float rstd = rsqrtf(var + EPS_LN);
    const float4* g4 = (const float4*)(lnqg + part * 8);
    const float4* b4 = (const float4*)(lnqb + part * 8);
    float4 g0 = g4[0], g1 = g4[1], bb0 = b4[0], bb1 = b4[1];
    float4 o0, o1;
    o0.x = (x0.x - mean) * rstd * g0.x + bb0.x;
    o0.y = (x0.y - mean) * rstd * g0.y + bb0.y;
    o0.z = (x0.z - mean) * rstd * g0.z + bb0.z;
    o0.w = (x0.w - mean) * rstd * g0.w + bb0.w;
    o1.x = (x1.x - mean) * rstd * g1.x + bb1.x;
    o1.y = (x1.y - mean) * rstd * g1.y + bb1.y;
    o1.z = (x1.z - mean) * rstd * g1.z + bb1.z;
    o1.w = (x1.w - mean) * rstd * g1.w + bb1.w;
    float4* xrow = (float4*)&xq[n * 128];
    xrow[part * 2] = o0;
    xrow[part * 2 + 1] = o1;
    __syncthreads();
    float o[8] = {0.f, 0.f, 0.f, 0.f, 0.f, 0.f, 0.f, 0.f};
    const float4* xv4 = (const float4*)&xq[n * 128];
#pragma unroll 4
    for (int j = 0; j < 32; j++) {
        float4 xv = xv4[j];
#pragma unroll
        for (int i = 0; i < 8; i++) {
            float4 w = ((const float4*)(Wq + (part * 8 + i) * 128))[j];
            o[i] += w.x * xv.x + w.y * xv.y + w.z * xv.z + w.w * xv.w;
        }
    }
    const float scale = 0.08838834764831845f;
#pragma unroll
    for (int i = 0; i < 8; i++)
        qn_g[row * 128 + part * 8 + i] = f2b(o[i] * scale);
}

// ---------------------------------------------------------------------------
// Kernel 1 (r5 proven, ~46us): 128 rows/block, 512 threads, async
// pre-swizzled W staging via global_load_lds. Unchanged (control).
// ---------------------------------------------------------------------------
__global__ __launch_bounds__(512, 4) void k_kvproj(
    const float* __restrict__ inp, const float* __restrict__ lng,
    const float* __restrict__ lnb, const unsigned short* __restrict__ Wk_sw,
    const unsigned short* __restrict__ Wv_sw, unsigned short* __restrict__ Kbf,
    unsigned short* __restrict__ Vt)
{
    __shared__ __align__(16) unsigned short W_lds[128 * 128];  // 32 KB
    __shared__ __align__(16) unsigned short T_lds[128 * 132];  // 33.8 KB
    const int tid = threadIdx.x;
    const int wave = tid >> 6, lane = tid & 63;
    const int l15 = lane & 15, q4 = lane >> 4;
    const int kof = q4 * 8;
    const int tile0 = blockIdx.x * 128;
    const int b = tile0 >> 12;
    const int hwbase = tile0 & (HW_ - 1);

    {
        const char* gw = (const char*)Wk_sw + wave * 4096 + lane * 16;
        char* lw = (char*)W_lds + wave * 4096;
#pragma unroll
        for (int j = 0; j < 4; j++)
            gload_lds16(gw + j * 1024, lw + j * 1024);
    }

    float x[4][8];
    {
        const float* rowp = inp + (tile0 + (wave << 4) + l15) * C_;
        float s = 0.f, ss = 0.f;
#pragma unroll
        for (int ks = 0; ks < 4; ks++) {
#pragma unroll
            for (int h = 0; h < 2; h++) {
                float4 v = *(const float4*)(rowp + ks * 32 + kof + h * 4);
                x[ks][h * 4 + 0] = v.x; x[ks][h * 4 + 1] = v.y;
                x[ks][h * 4 + 2] = v.z; x[ks][h * 4 + 3] = v.w;
                s += v.x + v.y + v.z + v.w;
                ss += v.x * v.x + v.y * v.y + v.z * v.z + v.w * v.w;
            }
        }
        s += __shfl_xor(s, 16);  s += __shfl_xor(s, 32);
        ss += __shfl_xor(ss, 16); ss += __shfl_xor(ss, 32);
        float mean = s * (1.f / 128.f);
        float var = ss * (1.f / 128.f) - mean * mean;
        float rstd = rsqrtf(var + EPS_LN);
#pragma unroll
        for (int ks = 0; ks < 4; ks++) {
#pragma unroll
            for (int h = 0; h < 2; h++) {
                float4 g = *(const float4*)(lng + ks * 32 + kof + h * 4);
                float4 bb = *(const float4*)(lnb + ks * 32 + kof + h * 4);
                x[ks][h * 4 + 0] = (x[ks][h * 4 + 0] - mean) * rstd * g.x + bb.x;
                x[ks][h * 4 + 1] = (x[ks][h * 4 + 1] - mean) * rstd * g.y + bb.y;
                x[ks][h * 4 + 2] = (x[ks][h * 4 + 2] - mean) * rstd * g.z + bb.z;
                x[ks][h * 4 + 3] = (x[ks][h * 4 + 3] - mean) * rstd * g.w + bb.w;
            }
        }
    }
    short8 af[4];
#pragma unroll
    for (int ks = 0; ks < 4; ks++) {
        union { short8 s8; unsigned u[4]; } p;
#pragma unroll
        for (int j = 0; j < 4; j++)
            p.u[j] = (unsigned)f2b(x[ks][2 * j]) | ((unsigned)f2b(x[ks][2 * j + 1]) << 16);
        af[ks] = p.s8;
    }

    __syncthreads();   // [1] Wk in LDS

    f32x4 acc[8];
#pragma unroll
    for (int nt = 0; nt < 8; nt++) {
        acc[nt] = (f32x4){0.f, 0.f, 0.f, 0.f};
#pragma unroll
        for (int ks = 0; ks < 4; ks++) {
            short8 bf = *(const short8*)&W_lds[(nt * 16 + l15) * 128 + ((ks * 4 + q4) ^ (l15 & 7)) * 8];
            acc[nt] = __builtin_amdgcn_mfma_f32_16x16x32_bf16(af[ks], bf, acc[nt], 0, 0, 0);
        }
    }
#pragma unroll
    for (int nt = 0; nt < 8; nt++) {
        int c = nt * 16 + l15;
#pragma unroll
        for (int i = 0; i < 4; i++)
            T_lds[((wave << 4) + (q4 << 2) + i) * 132 + c] = f2b(acc[nt][i]);
    }
    __syncthreads();   // [2]

    {
        int row = tid >> 2, part = tid & 3;
        uint4* dst = (uint4*)&Kbf[(b * HW_ + hwbase + row) * C_ + part * 32];
#pragma unroll
        for (int j = 0; j < 4; j++)
            dst[j] = *(const uint4*)&T_lds[row * 132 + part * 32 + j * 8];
    }
    {
        const char* gw = (const char*)Wv_sw + wave * 4096 + lane * 16;
        char* lw = (char*)W_lds + wave * 4096;
#pragma unroll
        for (int j = 0; j < 4; j++)
            gload_lds16(gw + j * 1024, lw + j * 1024);
    }
    __syncthreads();   // [3]

#pragma unroll
    for (int nt = 0; nt < 8; nt++) {
        acc[nt] = (f32x4){0.f, 0.f, 0.f, 0.f};
#pragma unroll
        for (int ks = 0; ks < 4; ks++) {
            short8 bf = *(const short8*)&W_lds[(nt * 16 + l15) * 128 + ((ks * 4 + q4) ^ (l15 & 7)) * 8];
            acc[nt] = __builtin_amdgcn_mfma_f32_16x16x32_bf16(af[ks], bf, acc[nt], 0, 0, 0);
        }
    }
#pragma unroll
    for (int nt = 0; nt < 8; nt++) {
        int c = nt * 16 + l15;
#pragma unroll
        for (int i = 0; i < 4; i++)
            T_lds[c * 132 + (wave << 4) + (q4 << 2) + i] = f2b(acc[nt][i]);
    }
    __syncthreads();   // [4]

    {
        int c = tid >> 2, part = tid & 3;
        uint4* dst = (uint4*)&Vt[(b * C_ + c) * HW_ + hwbase + part * 32];
#pragma unroll
        for (int j = 0; j < 4; j++)
            dst[j] = *(const uint4*)&T_lds[c * 132 + part * 32 + j * 8];
    }
}

// ---------------------------------------------------------------------------
// Kernel 2 v4 (per iter): 256 threads, grid (32, B). r8 theory: all global
// fragment reads (16 rows x 64B per instr) are request-rate limited ~2.2TB/s.
// v4 stages the K chunk (32KB) and V slice (32KB) into LDS via
// global_load_lds with PER-LANE XOR-PRE-SWIZZLED SOURCE addresses (address
// set per row is complete -> full-line coalesced requests; LDS linear holds
// swizzled layout; ds_read applies same XOR = conflict-free — kvproj's
// proven W-path pattern, guide m173 / rule #21). Kbf/Vt layouts unchanged.
// LDS 69.3KB -> 2 blocks/CU. 2 barriers.
// ---------------------------------------------------------------------------
__global__ __launch_bounds__(256) void k_attn(
    const unsigned short* __restrict__ qn_g, const unsigned short* __restrict__ Kbf,
    const unsigned short* __restrict__ Vt, float* __restrict__ Upart,
    float* __restrict__ rspart, float* __restrict__ a0_out, int last)
{
    __shared__ __align__(16) unsigned short Klds[128 * 128];   // 32 KB
    __shared__ __align__(16) unsigned short Vlds[128 * 128];   // 32 KB
    __shared__ __align__(16) unsigned short Pb[4][16 * 40];    // 5.1 KB
    __shared__ float rsw[4][16];
    const int b = blockIdx.y, chunk = blockIdx.x;
    const int tid = threadIdx.x;
    const int wave = tid >> 6, lane = tid & 63;
    const int l15 = lane & 15, q4 = lane >> 4;
    const int kof = q4 * 8;
    const int hwb_l = wave * 32;          // this wave's score hw window (local)
    const int cbase = wave * 32;          // this wave's PV c-slice

    // ---- stage K,V chunk -> LDS: swizzled per-lane source, linear LDS ----
    {
        const int rbase = wave * 4 + (lane >> 4);   // row this lane covers (per round)
        const int grp = lane & 15;                  // 16B group this lane covers
        const char* gK = (const char*)(Kbf + (size_t)(b * HW_ + chunk * 128) * C_);
        const char* gV = (const char*)Vt + ((size_t)b * C_ * HW_ + chunk * 128) * 2;
#pragma unroll
        for (int r = 0; r < 8; r++) {
            int row = r * 16 + rbase;               // hw row within chunk
            gload_lds16(gK + row * 256 + ((grp ^ (row & 7)) << 4),
                        (char*)Klds + r * 4096 + wave * 1024);
        }
#pragma unroll
        for (int r = 0; r < 8; r++) {
            int c = r * 16 + rbase;                 // channel row
            gload_lds16(gV + (size_t)c * HW_ * 2 + ((grp ^ (c & 7)) << 4),
                        (char*)Vlds + r * 4096 + wave * 1024);
        }
    }
    short8 aq[4];
#pragma unroll
    for (int ks = 0; ks < 4; ks++)
        aq[ks] = *(const short8*)&qn_g[(b * 16 + l15) * 128 + ks * 32 + kof];
    __syncthreads();   // [1] staging drained (barrier implies vmcnt(0))

    unsigned short* Pw = &Pb[wave][0];
    float rs[4] = {0.f, 0.f, 0.f, 0.f};
#pragma unroll
    for (int s = 0; s < 2; s++) {
        int rl = hwb_l + s * 16;                    // local hw row base
        f32x4 sa = {0.f, 0.f, 0.f, 0.f};
#pragma unroll
        for (int ks = 0; ks < 4; ks++) {
            short8 bk = *(const short8*)((const char*)Klds
                         + (rl + l15) * 256 + (((ks * 4 + q4) ^ (l15 & 7)) << 4));
            sa = __builtin_amdgcn_mfma_f32_16x16x32_bf16(aq[ks], bk, sa, 0, 0, 0);
        }
        float mx = fmaxf(fmaxf(sa[0], sa[1]), fmaxf(sa[2], sa[3]));
        mx = fmaxf(mx, __shfl_xor(mx, 16));
        mx = fmaxf(mx, __shfl_xor(mx, 32));
        float e[4]; float ssum = 0.f;
#pragma unroll
        for (int i = 0; i < 4; i++) { e[i] = __expf(sa[i] - mx); ssum += e[i]; }
        ssum += __shfl_xor(ssum, 16);
        ssum += __shfl_xor(ssum, 32);
        float inv = 1.f / ssum;
#pragma unroll
        for (int i = 0; i < 4; i++) {
            float a0v = e[i] * inv;
            rs[i] += a0v;
            if (last) a0_out[(b * 16 + q4 * 4 + i) * HW_ + chunk * 128 + rl + l15] = a0v;
            Pw[(q4 * 4 + i) * 40 + s * 16 + l15] = f2b(a0v);
        }
    }
    // rowsum (this wave's 32 hw)
#pragma unroll
    for (int i = 0; i < 4; i++) {
        rs[i] += __shfl_xor(rs[i], 1);
        rs[i] += __shfl_xor(rs[i], 2);
        rs[i] += __shfl_xor(rs[i], 4);
        rs[i] += __shfl_xor(rs[i], 8);
    }
    if (l15 == 0) {
#pragma unroll
        for (int i = 0; i < 4; i++) rsw[wave][q4 * 4 + i] = rs[i];
    }
    __syncthreads();   // [2] all waves' P visible

    // PV: accumulate over all 4 k-chunks (4 waves' P), finish c-slice
    f32x4 ua0 = {0.f, 0.f, 0.f, 0.f}, ua1 = {0.f, 0.f, 0.f, 0.f};
#pragma unroll
    for (int kc = 0; kc < 4; kc++) {
        short8 bp = *(const short8*)&Pb[kc][l15 * 40 + kof];
        short8 av0 = *(const short8*)((const char*)Vlds
                      + (cbase + l15) * 256 + (((kc * 4 + q4) ^ (l15 & 7)) << 4));
        short8 av1 = *(const short8*)((const char*)Vlds
                      + (cbase + 16 + l15) * 256 + (((kc * 4 + q4) ^ (l15 & 7)) << 4));
        ua0 = __builtin_amdgcn_mfma_f32_16x16x32_bf16(av0, bp, ua0, 0, 0, 0);
        ua1 = __builtin_amdgcn_mfma_f32_16x16x32_bf16(av1, bp, ua1, 0, 0, 0);
    }
    // direct Upart store: lane holds q = l15, c = cbase + ct*16 + q4*4 + i
    {
        float* up = Upart + (b * 32 + chunk) * 2048;
        *(f32x4*)&up[l15 * 128 + cbase + (q4 << 2)] = ua0;
        *(f32x4*)&up[l15 * 128 + cbase + 16 + (q4 << 2)] = ua1;
        if (tid < 16)
            rspart[(b * 32 + chunk) * 16 + tid] =
                rsw[0][tid] + rsw[1][tid] + rsw[2][tid] + rsw[3][tid];
    }
}

// ---------------------------------------------------------------------------
// Kernel 3 v5 (per iter): TWO rows per block, 512 threads, grid 256.
// Unchanged from r6/r7.
// ---------------------------------------------------------------------------
__global__ __launch_bounds__(512) void k_tail(
    const float* __restrict__ Upart, const float* __restrict__ rspart,
    const float* __restrict__ hsrc, float* __restrict__ q_buf,
    const unsigned short* __restrict__ wihT, const unsigned short* __restrict__ whhT,
    const float* __restrict__ bih, const float* __restrict__ bhh,
    const float* __restrict__ ln2g, const float* __restrict__ ln2b,
    const unsigned short* __restrict__ w1T, const float* __restrict__ b1,
    const unsigned short* __restrict__ w2T, const float* __restrict__ b2,
    const float* __restrict__ lnqg, const float* __restrict__ lnqb,
    const float* __restrict__ wqTf, unsigned short* __restrict__ qn_g,
    float* __restrict__ out_q, int last)
{
    __shared__ __align__(16) float red0[512], red1[512];
    __shared__ __align__(16) float u0_l[128], u1_l[128];
    __shared__ __align__(16) float h0_l[128], h1_l[128];
    __shared__ __align__(16) float y0_l[128], y1_l[128];
    __shared__ __align__(16) float z0_l[128], z1_l[128];
    __shared__ __align__(16) float g0_l[768], g1_l[768];
    __shared__ __align__(16) float f0_l[512], f1_l[512];
    __shared__ float srs0, srs1;
    const int tid = threadIdx.x;
    const int row0 = blockIdx.x * 2, row1 = row0 + 1;
    const int b = row0 >> 4, q0 = row0 & 15;

    {
        int c = tid & 127, h = tid >> 7;
        const float* upA = Upart + (b * 32 + h * 8) * 2048 + q0 * 128 + c;
        float a = 0.f, bv = 0.f;
#pragma unroll
        for (int ch = 0; ch < 8; ch++) {
            a  += upA[ch * 2048];
            bv += upA[ch * 2048 + 128];
        }
        red0[tid] = a; red1[tid] = bv;
        if (tid < 128) h0_l[tid] = hsrc[row0 * 128 + tid];
        else if (tid < 256) h1_l[tid - 128] = hsrc[row1 * 128 + (tid - 128)];
        if (tid >= 256 && tid < 288) {
            int t = tid - 256;
            float v = rspart[(b * 32 + t) * 16 + q0];
            v += __shfl_xor(v, 1); v += __shfl_xor(v, 2); v += __shfl_xor(v, 4);
            v += __shfl_xor(v, 8); v += __shfl_xor(v, 16);
            if (t == 0) srs0 = v;
        }
        if (tid >= 320 && tid < 352) {
            int t = tid - 320;
            float v = rspart[(b * 32 + t) * 16 + q0 + 1];
            v += __shfl_xor(v, 1); v += __shfl_xor(v, 2); v += __shfl_xor(v, 4);
            v += __shfl_xor(v, 8); v += __shfl_xor(v, 16);
            if (t == 0) srs1 = v;
        }
    }
    __syncthreads();
    if (tid < 128) {
        float s = red0[tid] + red0[tid + 128] + red0[tid + 256] + red0[tid + 384];
        u0_l[tid] = s / (srs0 + EPS_ATTN);
    } else if (tid < 256) {
        int c = tid - 128;
        float s = red1[c] + red1[c + 128] + red1[c + 256] + red1[c + 384];
        u1_l[c] = s / (srs1 + EPS_ATTN);
    }
    __syncthreads();
    {
        int o = tid;
        const uint2* wp; const float *sA, *sB; float bias;
        if (o < 384) { wp = (const uint2*)wihT + o; sA = u0_l; sB = u1_l; bias = bih[o]; }
        else         { wp = (const uint2*)whhT + (o - 384); sA = h0_l; sB = h1_l; bias = bhh[o - 384]; }
        float fa = 0.f, fb = 0.f;
#pragma unroll 4
        for (int g = 0; g < 32; g++) {
            uint2 w = wp[g * 384];
            float4 a4 = *(const float4*)&sA[g * 4];
            float4 b4 = *(const float4*)&sB[g * 4];
            float w0 = blo(w.x), w1v = bhi(w.x), w2v = blo(w.y), w3 = bhi(w.y);
            fa += w0 * a4.x + w1v * a4.y + w2v * a4.z + w3 * a4.w;
            fb += w0 * b4.x + w1v * b4.y + w2v * b4.z + w3 * b4.w;
        }
        g0_l[o] = fa + bias; g1_l[o] = fb + bias;
        if (tid < 256) {
            int o2 = tid + 512;
            const uint2* wp2 = (const uint2*)whhT + (o2 - 384);
            float fa2 = 0.f, fb2 = 0.f;
#pragma unroll 4
            for (int g = 0; g < 32; g++) {
                uint2 w = wp2[g * 384];
                float4 a4 = *(const float4*)&h0_l[g * 4];
                float4 b4 = *(const float4*)&h1_l[g * 4];
                float w0 = blo(w.x), w1v = bhi(w.x), w2v = blo(w.y), w3 = bhi(w.y);
                fa2 += w0 * a4.x + w1v * a4.y + w2v * a4.z + w3 * a4.w;
                fb2 += w0 * b4.x + w1v * b4.y + w2v * b4.z + w3 * b4.w;
            }
            float bias2 = bhh[o2 - 384];
            g0_l[o2] = fa2 + bias2; g1_l[o2] = fb2 + bias2;
        }
    }
    __syncthreads();
    if (tid < 256) {
        int c = tid & 127, r = tid >> 7;
        const float* gl = r ? g1_l : g0_l;
        const float* hl = r ? h1_l : h0_l;
        float* yl = r ? y1_l : y0_l;
        float ir = gl[c], iz = gl[128 + c], in_ = gl[256 + c];
        float hr = gl[384 + c], hz = gl[512 + c], hn = gl[640 + c];
        float rr = 1.f / (1.f + expf(-(ir + hr)));
        float zz = 1.f / (1.f + expf(-(iz + hz)));
        float nn = tanhf(in_ + rr * hn);
        yl[c] = (1.f - zz) * nn + zz * hl[c];
    }
    __syncthreads();
    {
        int r = tid >> 8;
        const float* yl = r ? y1_l : y0_l;
        int l = tid & 63;
        float v0 = yl[l], v1 = yl[l + 64];
        float s = v0 + v1, ss = v0 * v0 + v1 * v1;
#pragma unroll
        for (int off = 1; off < 64; off <<= 1) {
            s += __shfl_xor(s, off);
            ss += __shfl_xor(ss, off);
        }
        float mean = s * (1.f / 128.f);
        float var = ss * (1.f / 128.f) - mean * mean;
        float rstd = rsqrtf(var + EPS_LN);
        int c = tid & 255;
        if (c < 128) {
            float* zl = r ? z1_l : z0_l;
            zl[c] = (yl[c] - mean) * rstd * ln2g[c] + ln2b[c];
        }
    }
    __syncthreads();
    {
        const uint2* wp = (const uint2*)w1T + tid;
        float fa = 0.f, fb = 0.f;
#pragma unroll 4
        for (int g = 0; g < 32; g++) {
            uint2 w = wp[g * 512];
            float4 za = *(const float4*)&z0_l[g * 4];
            float4 zb = *(const float4*)&z1_l[g * 4];
            float w0 = blo(w.x), w1v = bhi(w.x), w2v = blo(w.y), w3 = bhi(w.y);
            fa += w0 * za.x + w1v * za.y + w2v * za.z + w3 * za.w;
            fb += w0 * zb.x + w1v * zb.y + w2v * zb.z + w3 * zb.w;
        }
        float bb = b1[tid];
        f0_l[tid] = fmaxf(fa + bb, 0.f);
        f1_l[tid] = fmaxf(fb + bb, 0.f);
    }
    __syncthreads();
    {
        int c = tid & 127, k4 = tid >> 7;
        const uint2* wp = (const uint2*)w2T + c;
        float fa = 0.f, fb = 0.f;
#pragma unroll 4
        for (int j = 0; j < 32; j++) {
            int g = k4 * 32 + j;
            uint2 w = wp[g * 128];
            float4 ha = *(const float4*)&f0_l[g * 4];
            float4 hb = *(const float4*)&f1_l[g * 4];
            float w0 = blo(w.x), w1v = bhi(w.x), w2v = blo(w.y), w3 = bhi(w.y);
            fa += w0 * ha.x + w1v * ha.y + w2v * ha.z + w3 * ha.w;
            fb += w0 * hb.x + w1v * hb.y + w2v * hb.z + w3 * hb.w;
        }
        red0[tid] = fa; red1[tid] = fb;
    }
    __syncthreads();
    if (tid < 128) {
        float f2 = red0[tid] + red0[tid + 128] + red0[tid + 256] + red0[tid + 384];
        float qn = y0_l[tid] + f2 + b2[tid];
        u0_l[tid] = qn;
        q_buf[row0 * 128 + tid] = qn;
        if (last) out_q[row0 * 128 + tid] = qn;
    } else if (tid < 256) {
        int c = tid - 128;
        float f2 = red1[c] + red1[c + 128] + red1[c + 256] + red1[c + 384];
        float qn = y1_l[c] + f2 + b2[c];
        u1_l[c] = qn;
        q_buf[row1 * 128 + c] = qn;
        if (last) out_q[row1 * 128 + c] = qn;
    }
    if (last) return;
    __syncthreads();
    {
        int r = tid >> 8;
        const float* yl = r ? u1_l : u0_l;
        int l = tid & 63;
        float v0 = yl[l], v1 = yl[l + 64];
        float s = v0 + v1, ss = v0 * v0 + v1 * v1;
#pragma unroll
        for (int off = 1; off < 64; off <<= 1) {
            s += __shfl_xor(s, off);
            ss += __shfl_xor(ss, off);
        }
        float mean = s * (1.f / 128.f);
        float var = ss * (1.f / 128.f) - mean * mean;
        float rstd = rsqrtf(var + EPS_LN);
        int c = tid & 255;
        if (c < 128) {
            float* zl = r ? z1_l : z0_l;
            zl[c] = (yl[c] - mean) * rstd * lnqg[c] + lnqb[c];
        }
    }
    __syncthreads();
    {
        int c = tid & 127, k4 = tid >> 7;
        const float4* wp = (const float4*)wqTf + c;
        float fa = 0.f, fb = 0.f;
#pragma unroll
        for (int j = 0; j < 8; j++) {
            int g = k4 * 8 + j;
            float4 w = wp[g * 128];
            float4 za = *(const float4*)&z0_l[g * 4];
            float4 zb = *(const float4*)&z1_l[g * 4];
            fa += w.x * za.x + w.y * za.y + w.z * za.z + w.w * za.w;
            fb += w.x * zb.x + w.y * zb.y + w.z * zb.z + w.w * zb.w;
        }
        red0[tid] = fa; red1[tid] = fb;
    }
    __syncthreads();
    if (tid < 128) {
        float qa = red0[tid] + red0[tid + 128] + red0[tid + 256] + red0[tid + 384];
        qn_g[row0 * 128 + tid] = f2b(qa * 0.08838834764831845f);
    } else if (tid < 256) {
        int c = tid - 128;
        float qa = red1[c] + red1[c + 128] + red1[c + 256] + red1[c + 384];
        qn_g[row1 * 128 + c] = f2b(qa * 0.08838834764831845f);
    }
}

// ---------------------------------------------------------------------------
extern "C" void kernel_launch(void* const* d_in, const int* in_sizes, int n_in,
                              void* d_out, int out_size, void* d_ws, size_t ws_size,
                              hipStream_t stream) {
    const float* inp     = (const float*)d_in[0];
    const float* query   = (const float*)d_in[1];
    const float* ln_kv_g = (const float*)d_in[2];
    const float* ln_kv_b = (const float*)d_in[3];
    const float* Wk      = (const float*)d_in[4];
    const float* Wv      = (const float*)d_in[5];
    const float* ln_q_g  = (const float*)d_in[6];
    const float* ln_q_b  = (const float*)d_in[7];
    const float* Wq      = (const float*)d_in[8];
    const float* gru_wih = (const float*)d_in[9];
    const float* gru_whh = (const float*)d_in[10];
    const float* gru_bih = (const float*)d_in[11];
    const float* gru_bhh = (const float*)d_in[12];
    const float* ln2_g   = (const float*)d_in[13];
    const float* ln2_b   = (const float*)d_in[14];
    const float* ffn_w1  = (const float*)d_in[15];
    const float* ffn_b1  = (const float*)d_in[16];
    const float* ffn_w2  = (const float*)d_in[17];
    const float* ffn_b2  = (const float*)d_in[18];

    char* ws = (char*)d_ws;
    unsigned short* Kbf    = (unsigned short*)ws;                  // 33554432
    unsigned short* Vt     = (unsigned short*)(ws + 33554432);     // 33554432
    float* q_buf           = (float*)(ws + 67108864);              // 262144
    float* Upart           = (float*)(ws + 67371008);              // 8388608
    float* rspart          = (float*)(ws + 75759616);              // 65536
    unsigned short* qn_g   = (unsigned short*)(ws + 75825152);     // 131072
    unsigned short* Wk_sw  = (unsigned short*)(ws + 75956224);     // 32768
    unsigned short* Wv_sw  = (unsigned short*)(ws + 75988992);     // 32768
    unsigned short* wihT   = (unsigned short*)(ws + 76021760);     // 98304
    unsigned short* whhT   = (unsigned short*)(ws + 76120064);     // 98304
    unsigned short* w1T    = (unsigned short*)(ws + 76218368);     // 131072
    unsigned short* w2T    = (unsigned short*)(ws + 76349440);     // 131072
    float* wqTf            = (float*)(ws + 76480512);              // 65536

    float* out_q  = (float*)d_out;
    float* out_a0 = out_q + B_ * N_ * C_;

    k_prep<<<dim3(304), dim3(256), 0, stream>>>(
        Wk, Wv, gru_wih, gru_whh, ffn_w1, ffn_w2,
        Wk_sw, Wv_sw, wihT, whhT, w1T, w2T,
        query, ln_q_g, ln_q_b, Wq, wqTf, qn_g);
    k_kvproj<<<dim3((B_ * HW_) / 128), dim3(512), 0, stream>>>(
        inp, ln_kv_g, ln_kv_b, Wk_sw, Wv_sw, Kbf, Vt);

    for (int it = 0; it < ITERS_; it++) {
        int last = (it == ITERS_ - 1) ? 1 : 0;
        const float* hsrc = (it == 0) ? query : q_buf;
        k_attn<<<dim3(32, B_), dim3(256), 0, stream>>>(
            qn_g, Kbf, Vt, Upart, rspart, out_a0, last);
        k_tail<<<dim3((B_ * N_) / 2), dim3(512), 0, stream>>>(
            Upart, rspart, hsrc, q_buf, wihT, whhT, gru_bih, gru_bhh,
            ln2_g, ln2_b, w1T, ffn_b1, w2T, ffn_b2,
            ln_q_g, ln_q_b, wqTf, qn_g, out_q, last);
    }
}